// Round 8
// baseline (214.307 us; speedup 1.0000x reference)
//
#include <hip/hip_runtime.h>
#include <math.h>

#define BATCH 128
#define LN_EPS 1e-5f

typedef short bf16x8 __attribute__((ext_vector_type(8)));
typedef short bf16x4 __attribute__((ext_vector_type(4)));
typedef float f32x4  __attribute__((ext_vector_type(4)));

__device__ __forceinline__ ushort f2bf(float f) {
    union { float f; unsigned u; } c; c.f = f;
    unsigned r = c.u + 0x7FFF + ((c.u >> 16) & 1);   // round-nearest-even
    return (ushort)(r >> 16);
}

__device__ __forceinline__ float fast_tanh(float v) {
    float e = __expf(2.f * v);
    return 1.f - 2.f / (e + 1.f);
}

// ---------------------------------------------------------------------------
// prep (unchanged):
//  idx < 32768: Wm23 = bf16 A-frag (tap-split layout) for cw2 (s=0), cw3 (s=1)
//  idx < 64   : composite token-conv x conv1 -> Wm1 (K=16 A-frag), cbt, W0c, W3c
// ---------------------------------------------------------------------------
__global__ void prep_kernel(const float* __restrict__ cw1, const float* __restrict__ cw2,
                            const float* __restrict__ cw3,
                            const float* __restrict__ w3, const float* __restrict__ b3,
                            const float* __restrict__ w5, const float* __restrict__ b5,
                            const float* __restrict__ w7, const float* __restrict__ b7,
                            const float* __restrict__ w9, const float* __restrict__ b9,
                            ushort* __restrict__ Wm23, ushort* __restrict__ Wm1,
                            float* __restrict__ cbt, float* __restrict__ W0c,
                            float* __restrict__ W3c) {
    int idx = blockIdx.x * 256 + threadIdx.x;      // grid covers 2*16384
    if (idx < 2 * 16384) {
        int s = idx >> 14, r = idx & 16383;
        int j = r & 7, l15 = (r >> 3) & 15, dt = (r >> 7) & 3;
        int quad = (r >> 9) & 3, k2 = (r >> 11) & 1, kk = (r >> 12) & 3;
        int dout = dt * 16 + l15, din = k2 * 32 + quad * 8 + j;
        const float* cw = (s == 0) ? cw2 : cw3;
        Wm23[idx] = f2bf(cw[dout * 256 + din * 4 + kk]);
    }
    if (idx < 64) {
        const int ch = idx;
        const float* cw1row = cw1 + ch * 256;
        float weff[12], cbtv[4], w0c[4], w3c[4];
#pragma unroll
        for (int j = 0; j < 12; ++j) weff[j] = 0.f;
#pragma unroll
        for (int k = 0; k < 4; ++k) { cbtv[k] = 0.f; w0c[k] = 0.f; w3c[k] = 0.f; }
        for (int din = 0; din < 64; ++din) {
            int ki = din & 3, g = din >> 2;
            float wl[9];
#pragma unroll
            for (int j = 0; j < 9; ++j) wl[j] = 0.f;
            float bias;
            if (ki == 0)      { for (int j = 0; j < 3; ++j) wl[3 + j] = w3[g * 3 + j]; bias = b3[g]; }
            else if (ki == 1) { for (int j = 0; j < 5; ++j) wl[2 + j] = w5[g * 5 + j]; bias = b5[g]; }
            else if (ki == 2) { for (int j = 0; j < 7; ++j) wl[1 + j] = w7[g * 7 + j]; bias = b7[g]; }
            else              { for (int j = 0; j < 9; ++j) wl[j]     = w9[g * 9 + j]; bias = b9[g]; }
#pragma unroll
            for (int kk = 0; kk < 4; ++kk) {
                float c = cw1row[din * 4 + kk];
                cbtv[kk] += c * bias;
#pragma unroll
                for (int u = 0; u < 9; ++u) weff[kk + u] += c * wl[u];
            }
            float c0 = cw1row[din * 4 + 0], c3 = cw1row[din * 4 + 3];
#pragma unroll
            for (int u = 0; u < 4; ++u) { w0c[u] += c0 * wl[5 + u]; w3c[u] += c3 * wl[u]; }
        }
        int dt = ch >> 4, l15 = ch & 15;
#pragma unroll
        for (int quad = 0; quad < 4; ++quad)
#pragma unroll
            for (int j = 0; j < 8; ++j) {
                int k = quad * 8 + j;
                Wm1[((quad * 4 + dt) * 16 + l15) * 8 + j] = f2bf(k < 12 ? weff[k] : 0.f);
            }
#pragma unroll
        for (int kk = 0; kk < 4; ++kk) cbt[kk * 64 + ch] = cbtv[kk];
#pragma unroll
        for (int u = 0; u < 4; ++u) { W0c[ch * 4 + u] = w0c[u]; W3c[ch * 4 + u] = w3c[u]; }
    }
}

// ---------------------------------------------------------------------------
// pe1c[l][ch] = cb1[ch] + conv1(pe)[ch][l] + valid token-bias terms
// ---------------------------------------------------------------------------
__global__ __launch_bounds__(256, 2)
void pe1_kernel(const float* __restrict__ cw1, const float* __restrict__ cb1,
                const float* __restrict__ cbt, float* __restrict__ pe1c) {
    __shared__ float tile[64][132];
    const int tid = threadIdx.x;
    const int l0 = blockIdx.x * 64;
    const int pin0 = 2 * l0 - 1;
    for (int idx = tid; idx < 64 * 130; idx += 256) {
        int d = idx / 130, pp = idx - d * 130;
        int p = pin0 + pp;
        float v = 0.f;
        if (p >= 0 && p < 4096) {
            float dv = __expf((float)(d & ~1) * -0.14391156831212787f);  // -ln(1e4)/64
            float ang = (float)p * dv;
            v = (d & 1) ? __cosf(ang) : __sinf(ang);
        }
        tile[d][pp] = v;
    }
    __syncthreads();
    const int lane = tid & 63, wv = tid >> 6;
    const int l = l0 + lane, db = wv * 16;
    float acc[16];
#pragma unroll
    for (int j = 0; j < 16; ++j) {
        int ch = db + j;
        float a = cb1[ch] + cbt[64 + ch] + cbt[128 + ch];
        if (l > 0) a += cbt[ch];
        if (l < 2047) a += cbt[192 + ch];
        acc[j] = a;
    }
    for (int din = 0; din < 64; ++din) {
        float v0 = tile[din][2 * lane + 0], v1 = tile[din][2 * lane + 1];
        float v2 = tile[din][2 * lane + 2], v3 = tile[din][2 * lane + 3];
        const float* wb = cw1 + din * 4;
#pragma unroll
        for (int j = 0; j < 16; ++j) {
            const float* wj = wb + (db + j) * 256;
            acc[j] = fmaf(v0, wj[0], fmaf(v1, wj[1], fmaf(v2, wj[2], fmaf(v3, wj[3], acc[j]))));
        }
    }
#pragma unroll
    for (int j = 0; j < 16; ++j) pe1c[(size_t)l * 64 + db + j] = acc[j];
}

// ---------------------------------------------------------------------------
// Fully fused pipeline, 32 final positions per block (2048 blocks, ~35 KB LDS
// -> 4 blocks/CU). Single row-addressed tiles (no parity split):
//   T1[m] = h1[qstart+m], qstart = 4g0-3, m<134 valid (sized 164: stage2's
//           discarded MFMA rows read up to 161 in-bounds).
//   T2[n] = h2[2g0-1+n], n<66.
// LN gamma/beta + conv biases staged once into LDS (PL).
// ---------------------------------------------------------------------------
__global__ __launch_bounds__(256, 4)
void mega_kernel(const float* __restrict__ x,
                 const ushort* __restrict__ Wm1, const ushort* __restrict__ Wm23,
                 const float* __restrict__ pe1c,
                 const float* __restrict__ W0c, const float* __restrict__ W3c,
                 const float* __restrict__ lg1, const float* __restrict__ lb1,
                 const float* __restrict__ cb2, const float* __restrict__ lg2,
                 const float* __restrict__ lb2, const float* __restrict__ cb3,
                 float* __restrict__ out) {
    const int b = blockIdx.y;
    const int g0 = blockIdx.x * 32;
    const int tid = threadIdx.x;

    __shared__ __align__(16) ushort xs[320];
    __shared__ __align__(16) ushort T1[164][72];
    __shared__ __align__(16) ushort T2[66][72];
    __shared__ __align__(16) float PL[384];   // lg1|lb1|cb2|lg2|lb2|cb3

    // ---- stage x window + params ----
    for (int i = tid; i < 320; i += 256) {
        int g = 8 * g0 - 11 + i;
        float v = (g >= 0 && g < 4096) ? x[b * 4096 + g] : 0.f;
        xs[i] = f2bf(v);
    }
    if (tid < 64)        PL[tid] = lg1[tid];
    else if (tid < 128)  PL[tid] = lb1[tid - 64];
    else if (tid < 192)  PL[tid] = cb2[tid - 128];
    else                 PL[tid] = lg2[tid - 192];
    if (tid < 64)        PL[256 + tid] = lb2[tid];
    else if (tid < 128)  PL[256 + tid] = cb3[tid - 64];
    __syncthreads();

    const int wv = tid >> 6, lane = tid & 63;
    const int quad = lane >> 4, l15 = lane & 15;

    // ================= stage 1: h1 rows m<134, q = qstart+m ================
    {
        const int qstart = 4 * g0 - 3;
        bf16x8 afr1[4];
#pragma unroll
        for (int dt = 0; dt < 4; ++dt)
            afr1[dt] = *(const bf16x8*)&Wm1[((quad * 4 + dt) * 16 + l15) * 8];
        for (int t = wv; t < 9; t += 4) {
            const int m = t * 16 + l15;
            union { bf16x8 v; unsigned u[4]; } tmp;
            const unsigned* p = (const unsigned*)&xs[2 * m + 8 * quad];
#pragma unroll
            for (int i = 0; i < 4; ++i) tmp.u[i] = p[i];
            f32x4 a1[4];
#pragma unroll
            for (int dt = 0; dt < 4; ++dt)
                a1[dt] = __builtin_amdgcn_mfma_f32_16x16x32_bf16(
                    afr1[dt], tmp.v, (f32x4)0.f, 0, 0, 0);
            if (m < 134) {                       // shfl partners share m
                const int q = qstart + m;
                ushort* dst = &T1[m][0];
                if (q >= 0 && q < 2048) {
                    float v[16];
                    const float* pb_ = pe1c + (size_t)q * 64;
#pragma unroll
                    for (int dt = 0; dt < 4; ++dt) {
                        float4 pv = *(const float4*)(pb_ + dt * 16 + quad * 4);
                        v[dt * 4 + 0] = a1[dt][0] + pv.x;
                        v[dt * 4 + 1] = a1[dt][1] + pv.y;
                        v[dt * 4 + 2] = a1[dt][2] + pv.z;
                        v[dt * 4 + 3] = a1[dt][3] + pv.w;
                    }
                    if (q == 0 || q == 2047) {   // conv1 pads emb, not x
                        const float* Wc = (q == 0) ? W0c : W3c;
                        const float* xe = x + b * 4096 + ((q == 0) ? 0 : 4092);
                        float x0 = xe[0], x1 = xe[1], x2 = xe[2], x3 = xe[3];
#pragma unroll
                        for (int dt = 0; dt < 4; ++dt)
#pragma unroll
                            for (int r = 0; r < 4; ++r) {
                                const float* wc = Wc + (dt * 16 + quad * 4 + r) * 4;
                                v[dt * 4 + r] -= wc[0] * x0 + wc[1] * x1 + wc[2] * x2 + wc[3] * x3;
                            }
                    }
#pragma unroll
                    for (int i = 0; i < 16; ++i) v[i] = fast_tanh(v[i]);
                    float s = 0.f;
#pragma unroll
                    for (int i = 0; i < 16; ++i) s += v[i];
                    s += __shfl_xor(s, 16, 64);
                    s += __shfl_xor(s, 32, 64);
                    float mean = s * 0.015625f;
                    float qq = 0.f;
#pragma unroll
                    for (int i = 0; i < 16; ++i) { float d = v[i] - mean; qq = fmaf(d, d, qq); }
                    qq += __shfl_xor(qq, 16, 64);
                    qq += __shfl_xor(qq, 32, 64);
                    float rstd = rsqrtf(qq * 0.015625f + LN_EPS);
#pragma unroll
                    for (int dt = 0; dt < 4; ++dt) {
                        float4 gv = *(const float4*)&PL[0 + dt * 16 + quad * 4];
                        float4 bv = *(const float4*)&PL[64 + dt * 16 + quad * 4];
                        bf16x4 pk;
                        pk[0] = (short)f2bf((v[dt * 4 + 0] - mean) * rstd * gv.x + bv.x);
                        pk[1] = (short)f2bf((v[dt * 4 + 1] - mean) * rstd * gv.y + bv.y);
                        pk[2] = (short)f2bf((v[dt * 4 + 2] - mean) * rstd * gv.z + bv.z);
                        pk[3] = (short)f2bf((v[dt * 4 + 3] - mean) * rstd * gv.w + bv.w);
                        *(bf16x4*)(dst + dt * 16 + quad * 4) = pk;
                    }
                } else {
                    bf16x4 z; z[0] = 0; z[1] = 0; z[2] = 0; z[3] = 0;
#pragma unroll
                    for (int dt = 0; dt < 4; ++dt)
                        *(bf16x4*)(dst + dt * 16 + quad * 4) = z;
                }
            }
        }
    }
    __syncthreads();

    // ================= stage 2: h2 rows n<66, p = 2g0-1+n ==================
    for (int t = wv; t < 5; t += 4) {
        const int n = t * 16 + l15;
        f32x4 a2[4];
#pragma unroll
        for (int dt = 0; dt < 4; ++dt) a2[dt] = (f32x4)0.f;
#pragma unroll
        for (int kk = 0; kk < 4; ++kk) {
            const int row = 2 * n + kk;          // <= 161 < 164, in-bounds
#pragma unroll
            for (int k2 = 0; k2 < 2; ++k2) {
                bf16x8 bfr = *(const bf16x8*)&T1[row][k2 * 32 + quad * 8];
                const ushort* wb = Wm23 + ((((kk * 2 + k2) * 4 + quad) * 4) * 16) * 8;
#pragma unroll
                for (int dt = 0; dt < 4; ++dt) {
                    bf16x8 afr = *(const bf16x8*)(wb + ((size_t)(dt * 16 + l15)) * 8);
                    a2[dt] = __builtin_amdgcn_mfma_f32_16x16x32_bf16(afr, bfr, a2[dt], 0, 0, 0);
                }
            }
        }
        if (n < 66) {
            const int p = 2 * g0 - 1 + n;
            ushort* dst = &T2[n][0];
            if (p >= 0 && p < 1024) {
                float v[16];
#pragma unroll
                for (int dt = 0; dt < 4; ++dt) {
                    float4 cv = *(const float4*)&PL[128 + dt * 16 + quad * 4];
                    v[dt * 4 + 0] = fast_tanh(a2[dt][0] + cv.x);
                    v[dt * 4 + 1] = fast_tanh(a2[dt][1] + cv.y);
                    v[dt * 4 + 2] = fast_tanh(a2[dt][2] + cv.z);
                    v[dt * 4 + 3] = fast_tanh(a2[dt][3] + cv.w);
                }
                float s = 0.f;
#pragma unroll
                for (int i = 0; i < 16; ++i) s += v[i];
                s += __shfl_xor(s, 16, 64);
                s += __shfl_xor(s, 32, 64);
                float mean = s * 0.015625f;
                float qq = 0.f;
#pragma unroll
                for (int i = 0; i < 16; ++i) { float d = v[i] - mean; qq = fmaf(d, d, qq); }
                qq += __shfl_xor(qq, 16, 64);
                qq += __shfl_xor(qq, 32, 64);
                float rstd = rsqrtf(qq * 0.015625f + LN_EPS);
#pragma unroll
                for (int dt = 0; dt < 4; ++dt) {
                    float4 gv = *(const float4*)&PL[192 + dt * 16 + quad * 4];
                    float4 bv = *(const float4*)&PL[256 + dt * 16 + quad * 4];
                    bf16x4 pk;
                    pk[0] = (short)f2bf((v[dt * 4 + 0] - mean) * rstd * gv.x + bv.x);
                    pk[1] = (short)f2bf((v[dt * 4 + 1] - mean) * rstd * gv.y + bv.y);
                    pk[2] = (short)f2bf((v[dt * 4 + 2] - mean) * rstd * gv.z + bv.z);
                    pk[3] = (short)f2bf((v[dt * 4 + 3] - mean) * rstd * gv.w + bv.w);
                    *(bf16x4*)(dst + dt * 16 + quad * 4) = pk;
                }
            } else {
                bf16x4 z; z[0] = 0; z[1] = 0; z[2] = 0; z[3] = 0;
#pragma unroll
                for (int dt = 0; dt < 4; ++dt)
                    *(bf16x4*)(dst + dt * 16 + quad * 4) = z;
            }
        }
    }
    __syncthreads();

    // ================= stage 3: final l = g0 + m3, m3 = wv*16+l15 (wv<2) ===
    if (wv < 2) {
        const int m3 = wv * 16 + l15;
        f32x4 a3[4];
#pragma unroll
        for (int dt = 0; dt < 4; ++dt) a3[dt] = (f32x4)0.f;
        const ushort* Wg3 = Wm23 + 16384;
#pragma unroll
        for (int kk = 0; kk < 4; ++kk) {
            const int row = 2 * m3 + kk;         // <= 65 < 66
#pragma unroll
            for (int k2 = 0; k2 < 2; ++k2) {
                bf16x8 bfr = *(const bf16x8*)&T2[row][k2 * 32 + quad * 8];
                const ushort* wb = Wg3 + ((((kk * 2 + k2) * 4 + quad) * 4) * 16) * 8;
#pragma unroll
                for (int dt = 0; dt < 4; ++dt) {
                    bf16x8 afr = *(const bf16x8*)(wb + ((size_t)(dt * 16 + l15)) * 8);
                    a3[dt] = __builtin_amdgcn_mfma_f32_16x16x32_bf16(afr, bfr, a3[dt], 0, 0, 0);
                }
            }
        }
        const int l = g0 + m3;
        float* ob = out + ((size_t)(b * 512) + l) * 64;
#pragma unroll
        for (int dt = 0; dt < 4; ++dt) {
            float4 cv = *(const float4*)&PL[320 + dt * 16 + quad * 4];
            float4 st = make_float4(fast_tanh(a3[dt][0] + cv.x),
                                    fast_tanh(a3[dt][1] + cv.y),
                                    fast_tanh(a3[dt][2] + cv.z),
                                    fast_tanh(a3[dt][3] + cv.w));
            *(float4*)(ob + dt * 16 + quad * 4) = st;
        }
    }
}

extern "C" void kernel_launch(void* const* d_in, const int* in_sizes, int n_in,
                              void* d_out, int out_size, void* d_ws, size_t ws_size,
                              hipStream_t stream) {
    (void)in_sizes; (void)n_in; (void)out_size; (void)ws_size;
    const float* x   = (const float*)d_in[0];
    const float* w3  = (const float*)d_in[1];
    const float* b3  = (const float*)d_in[2];
    const float* w5  = (const float*)d_in[3];
    const float* b5  = (const float*)d_in[4];
    const float* w7  = (const float*)d_in[5];
    const float* b7  = (const float*)d_in[6];
    const float* w9  = (const float*)d_in[7];
    const float* b9  = (const float*)d_in[8];
    const float* cw1 = (const float*)d_in[9];
    const float* cb1 = (const float*)d_in[10];
    const float* cw2 = (const float*)d_in[11];
    const float* cb2 = (const float*)d_in[12];
    const float* cw3 = (const float*)d_in[13];
    const float* cb3 = (const float*)d_in[14];
    const float* lg1 = (const float*)d_in[15];
    const float* lb1 = (const float*)d_in[16];
    const float* lg2 = (const float*)d_in[17];
    const float* lb2 = (const float*)d_in[18];
    float* out = (float*)d_out;

    // ws layout (bytes) — ~590 KB total, no HBM intermediates:
    char* w = (char*)d_ws;
    ushort* Wm23 = (ushort*)(w + 0);          //  65536 B (2 x 16384 bf16)
    ushort* Wm1  = (ushort*)(w + 65536);      //   4096 B (2048 bf16)
    float*  cbt  = (float*)(w + 69632);       //   1024 B
    float*  W0c  = (float*)(w + 70656);       //   1024 B
    float*  W3c  = (float*)(w + 71680);       //   1024 B
    float*  pe1c = (float*)(w + 72704);       // 524288 B (2048 x 64 fp32)

    prep_kernel<<<128, 256, 0, stream>>>(cw1, cw2, cw3, w3, b3, w5, b5, w7, b7, w9, b9,
                                         Wm23, Wm1, cbt, W0c, W3c);
    pe1_kernel<<<32, 256, 0, stream>>>(cw1, cb1, cbt, pe1c);
    mega_kernel<<<dim3(16, BATCH), 256, 0, stream>>>(
        x, Wm1, Wm23, pe1c, W0c, W3c, lg1, lb1, cb2, lg2, lb2, cb3, out);
}

// Round 9
// 200.236 us; speedup vs baseline: 1.0703x; 1.0703x over previous
//
#include <hip/hip_runtime.h>
#include <math.h>

#define BATCH 128
#define LN_EPS 1e-5f

typedef short bf16x8 __attribute__((ext_vector_type(8)));
typedef short bf16x4 __attribute__((ext_vector_type(4)));
typedef float f32x4  __attribute__((ext_vector_type(4)));

__device__ __forceinline__ ushort f2bf(float f) {
    union { float f; unsigned u; } c; c.f = f;
    unsigned r = c.u + 0x7FFF + ((c.u >> 16) & 1);   // round-nearest-even
    return (ushort)(r >> 16);
}

__device__ __forceinline__ float fast_tanh(float v) {
    float e = __expf(2.f * v);
    return 1.f - 2.f / (e + 1.f);
}

// ---------------------------------------------------------------------------
// prep (unchanged):
//  idx < 32768: Wm23 = bf16 A-frag (tap-split layout) for cw2 (s=0), cw3 (s=1)
//  idx < 64   : composite token-conv x conv1 -> Wm1 (K=16 A-frag), cbt, W0c, W3c
// ---------------------------------------------------------------------------
__global__ void prep_kernel(const float* __restrict__ cw1, const float* __restrict__ cw2,
                            const float* __restrict__ cw3,
                            const float* __restrict__ w3, const float* __restrict__ b3,
                            const float* __restrict__ w5, const float* __restrict__ b5,
                            const float* __restrict__ w7, const float* __restrict__ b7,
                            const float* __restrict__ w9, const float* __restrict__ b9,
                            ushort* __restrict__ Wm23, ushort* __restrict__ Wm1,
                            float* __restrict__ cbt, float* __restrict__ W0c,
                            float* __restrict__ W3c) {
    int idx = blockIdx.x * 256 + threadIdx.x;      // grid covers 2*16384
    if (idx < 2 * 16384) {
        int s = idx >> 14, r = idx & 16383;
        int j = r & 7, l15 = (r >> 3) & 15, dt = (r >> 7) & 3;
        int quad = (r >> 9) & 3, k2 = (r >> 11) & 1, kk = (r >> 12) & 3;
        int dout = dt * 16 + l15, din = k2 * 32 + quad * 8 + j;
        const float* cw = (s == 0) ? cw2 : cw3;
        Wm23[idx] = f2bf(cw[dout * 256 + din * 4 + kk]);
    }
    if (idx < 64) {
        const int ch = idx;
        const float* cw1row = cw1 + ch * 256;
        float weff[12], cbtv[4], w0c[4], w3c[4];
#pragma unroll
        for (int j = 0; j < 12; ++j) weff[j] = 0.f;
#pragma unroll
        for (int k = 0; k < 4; ++k) { cbtv[k] = 0.f; w0c[k] = 0.f; w3c[k] = 0.f; }
        for (int din = 0; din < 64; ++din) {
            int ki = din & 3, g = din >> 2;
            float wl[9];
#pragma unroll
            for (int j = 0; j < 9; ++j) wl[j] = 0.f;
            float bias;
            if (ki == 0)      { for (int j = 0; j < 3; ++j) wl[3 + j] = w3[g * 3 + j]; bias = b3[g]; }
            else if (ki == 1) { for (int j = 0; j < 5; ++j) wl[2 + j] = w5[g * 5 + j]; bias = b5[g]; }
            else if (ki == 2) { for (int j = 0; j < 7; ++j) wl[1 + j] = w7[g * 7 + j]; bias = b7[g]; }
            else              { for (int j = 0; j < 9; ++j) wl[j]     = w9[g * 9 + j]; bias = b9[g]; }
#pragma unroll
            for (int kk = 0; kk < 4; ++kk) {
                float c = cw1row[din * 4 + kk];
                cbtv[kk] += c * bias;
#pragma unroll
                for (int u = 0; u < 9; ++u) weff[kk + u] += c * wl[u];
            }
            float c0 = cw1row[din * 4 + 0], c3 = cw1row[din * 4 + 3];
#pragma unroll
            for (int u = 0; u < 4; ++u) { w0c[u] += c0 * wl[5 + u]; w3c[u] += c3 * wl[u]; }
        }
        int dt = ch >> 4, l15 = ch & 15;
#pragma unroll
        for (int quad = 0; quad < 4; ++quad)
#pragma unroll
            for (int j = 0; j < 8; ++j) {
                int k = quad * 8 + j;
                Wm1[((quad * 4 + dt) * 16 + l15) * 8 + j] = f2bf(k < 12 ? weff[k] : 0.f);
            }
#pragma unroll
        for (int kk = 0; kk < 4; ++kk) cbt[kk * 64 + ch] = cbtv[kk];
#pragma unroll
        for (int u = 0; u < 4; ++u) { W0c[ch * 4 + u] = w0c[u]; W3c[ch * 4 + u] = w3c[u]; }
    }
}

// ---------------------------------------------------------------------------
// pe1c[l][ch] = cb1[ch] + conv1(pe)[ch][l] + valid token-bias terms
// ---------------------------------------------------------------------------
__global__ __launch_bounds__(256, 2)
void pe1_kernel(const float* __restrict__ cw1, const float* __restrict__ cb1,
                const float* __restrict__ cbt, float* __restrict__ pe1c) {
    __shared__ float tile[64][132];
    const int tid = threadIdx.x;
    const int l0 = blockIdx.x * 64;
    const int pin0 = 2 * l0 - 1;
    for (int idx = tid; idx < 64 * 130; idx += 256) {
        int d = idx / 130, pp = idx - d * 130;
        int p = pin0 + pp;
        float v = 0.f;
        if (p >= 0 && p < 4096) {
            float dv = __expf((float)(d & ~1) * -0.14391156831212787f);  // -ln(1e4)/64
            float ang = (float)p * dv;
            v = (d & 1) ? __cosf(ang) : __sinf(ang);
        }
        tile[d][pp] = v;
    }
    __syncthreads();
    const int lane = tid & 63, wv = tid >> 6;
    const int l = l0 + lane, db = wv * 16;
    float acc[16];
#pragma unroll
    for (int j = 0; j < 16; ++j) {
        int ch = db + j;
        float a = cb1[ch] + cbt[64 + ch] + cbt[128 + ch];
        if (l > 0) a += cbt[ch];
        if (l < 2047) a += cbt[192 + ch];
        acc[j] = a;
    }
    for (int din = 0; din < 64; ++din) {
        float v0 = tile[din][2 * lane + 0], v1 = tile[din][2 * lane + 1];
        float v2 = tile[din][2 * lane + 2], v3 = tile[din][2 * lane + 3];
        const float* wb = cw1 + din * 4;
#pragma unroll
        for (int j = 0; j < 16; ++j) {
            const float* wj = wb + (db + j) * 256;
            acc[j] = fmaf(v0, wj[0], fmaf(v1, wj[1], fmaf(v2, wj[2], fmaf(v3, wj[3], acc[j]))));
        }
    }
#pragma unroll
    for (int j = 0; j < 16; ++j) pe1c[(size_t)l * 64 + db + j] = acc[j];
}

// ---------------------------------------------------------------------------
// Fully fused pipeline, 32 final positions per block (2048 blocks, ~35 KB LDS).
// __launch_bounds__(256,2): empirically (r8) the ",4" variant caps VGPR at 64
// and spills 125 MB/dispatch to scratch; ",2" lets the ~112-VGPR working set
// stay in registers, and 112 VGPR still admits 4 waves/SIMD (4 blocks/CU).
//   T1[m] = h1[qstart+m], qstart = 4g0-3, m<134 valid (sized 164: stage2's
//           discarded MFMA rows read up to 161 in-bounds).
//   T2[n] = h2[2g0-1+n], n<66.
// LN gamma/beta + conv biases staged once into LDS (PL).
// ---------------------------------------------------------------------------
__global__ __launch_bounds__(256, 2)
void mega_kernel(const float* __restrict__ x,
                 const ushort* __restrict__ Wm1, const ushort* __restrict__ Wm23,
                 const float* __restrict__ pe1c,
                 const float* __restrict__ W0c, const float* __restrict__ W3c,
                 const float* __restrict__ lg1, const float* __restrict__ lb1,
                 const float* __restrict__ cb2, const float* __restrict__ lg2,
                 const float* __restrict__ lb2, const float* __restrict__ cb3,
                 float* __restrict__ out) {
    const int b = blockIdx.y;
    const int g0 = blockIdx.x * 32;
    const int tid = threadIdx.x;

    __shared__ __align__(16) ushort xs[320];
    __shared__ __align__(16) ushort T1[164][72];
    __shared__ __align__(16) ushort T2[66][72];
    __shared__ __align__(16) float PL[384];   // lg1|lb1|cb2|lg2|lb2|cb3

    // ---- stage x window + params ----
    for (int i = tid; i < 320; i += 256) {
        int g = 8 * g0 - 11 + i;
        float v = (g >= 0 && g < 4096) ? x[b * 4096 + g] : 0.f;
        xs[i] = f2bf(v);
    }
    if (tid < 64)        PL[tid] = lg1[tid];
    else if (tid < 128)  PL[tid] = lb1[tid - 64];
    else if (tid < 192)  PL[tid] = cb2[tid - 128];
    else                 PL[tid] = lg2[tid - 192];
    if (tid < 64)        PL[256 + tid] = lb2[tid];
    else if (tid < 128)  PL[256 + tid] = cb3[tid - 64];
    __syncthreads();

    const int wv = tid >> 6, lane = tid & 63;
    const int quad = lane >> 4, l15 = lane & 15;

    // ================= stage 1: h1 rows m<134, q = qstart+m ================
    {
        const int qstart = 4 * g0 - 3;
        bf16x8 afr1[4];
#pragma unroll
        for (int dt = 0; dt < 4; ++dt)
            afr1[dt] = *(const bf16x8*)&Wm1[((quad * 4 + dt) * 16 + l15) * 8];
        for (int t = wv; t < 9; t += 4) {
            const int m = t * 16 + l15;
            union { bf16x8 v; unsigned u[4]; } tmp;
            const unsigned* p = (const unsigned*)&xs[2 * m + 8 * quad];
#pragma unroll
            for (int i = 0; i < 4; ++i) tmp.u[i] = p[i];
            f32x4 a1[4];
#pragma unroll
            for (int dt = 0; dt < 4; ++dt)
                a1[dt] = __builtin_amdgcn_mfma_f32_16x16x32_bf16(
                    afr1[dt], tmp.v, (f32x4)0.f, 0, 0, 0);
            if (m < 134) {                       // shfl partners share m
                const int q = qstart + m;
                ushort* dst = &T1[m][0];
                if (q >= 0 && q < 2048) {
                    float v[16];
                    const float* pb_ = pe1c + (size_t)q * 64;
#pragma unroll
                    for (int dt = 0; dt < 4; ++dt) {
                        float4 pv = *(const float4*)(pb_ + dt * 16 + quad * 4);
                        v[dt * 4 + 0] = a1[dt][0] + pv.x;
                        v[dt * 4 + 1] = a1[dt][1] + pv.y;
                        v[dt * 4 + 2] = a1[dt][2] + pv.z;
                        v[dt * 4 + 3] = a1[dt][3] + pv.w;
                    }
                    if (q == 0 || q == 2047) {   // conv1 pads emb, not x
                        const float* Wc = (q == 0) ? W0c : W3c;
                        const float* xe = x + b * 4096 + ((q == 0) ? 0 : 4092);
                        float x0 = xe[0], x1 = xe[1], x2 = xe[2], x3 = xe[3];
#pragma unroll
                        for (int dt = 0; dt < 4; ++dt)
#pragma unroll
                            for (int r = 0; r < 4; ++r) {
                                const float* wc = Wc + (dt * 16 + quad * 4 + r) * 4;
                                v[dt * 4 + r] -= wc[0] * x0 + wc[1] * x1 + wc[2] * x2 + wc[3] * x3;
                            }
                    }
#pragma unroll
                    for (int i = 0; i < 16; ++i) v[i] = fast_tanh(v[i]);
                    float s = 0.f;
#pragma unroll
                    for (int i = 0; i < 16; ++i) s += v[i];
                    s += __shfl_xor(s, 16, 64);
                    s += __shfl_xor(s, 32, 64);
                    float mean = s * 0.015625f;
                    float qq = 0.f;
#pragma unroll
                    for (int i = 0; i < 16; ++i) { float d = v[i] - mean; qq = fmaf(d, d, qq); }
                    qq += __shfl_xor(qq, 16, 64);
                    qq += __shfl_xor(qq, 32, 64);
                    float rstd = rsqrtf(qq * 0.015625f + LN_EPS);
#pragma unroll
                    for (int dt = 0; dt < 4; ++dt) {
                        float4 gv = *(const float4*)&PL[0 + dt * 16 + quad * 4];
                        float4 bv = *(const float4*)&PL[64 + dt * 16 + quad * 4];
                        bf16x4 pk;
                        pk[0] = (short)f2bf((v[dt * 4 + 0] - mean) * rstd * gv.x + bv.x);
                        pk[1] = (short)f2bf((v[dt * 4 + 1] - mean) * rstd * gv.y + bv.y);
                        pk[2] = (short)f2bf((v[dt * 4 + 2] - mean) * rstd * gv.z + bv.z);
                        pk[3] = (short)f2bf((v[dt * 4 + 3] - mean) * rstd * gv.w + bv.w);
                        *(bf16x4*)(dst + dt * 16 + quad * 4) = pk;
                    }
                } else {
                    bf16x4 z; z[0] = 0; z[1] = 0; z[2] = 0; z[3] = 0;
#pragma unroll
                    for (int dt = 0; dt < 4; ++dt)
                        *(bf16x4*)(dst + dt * 16 + quad * 4) = z;
                }
            }
        }
    }
    __syncthreads();

    // ================= stage 2: h2 rows n<66, p = 2g0-1+n ==================
    for (int t = wv; t < 5; t += 4) {
        const int n = t * 16 + l15;
        f32x4 a2[4];
#pragma unroll
        for (int dt = 0; dt < 4; ++dt) a2[dt] = (f32x4)0.f;
#pragma unroll
        for (int kk = 0; kk < 4; ++kk) {
            const int row = 2 * n + kk;          // <= 161 < 164, in-bounds
#pragma unroll
            for (int k2 = 0; k2 < 2; ++k2) {
                bf16x8 bfr = *(const bf16x8*)&T1[row][k2 * 32 + quad * 8];
                const ushort* wb = Wm23 + ((((kk * 2 + k2) * 4 + quad) * 4) * 16) * 8;
#pragma unroll
                for (int dt = 0; dt < 4; ++dt) {
                    bf16x8 afr = *(const bf16x8*)(wb + ((size_t)(dt * 16 + l15)) * 8);
                    a2[dt] = __builtin_amdgcn_mfma_f32_16x16x32_bf16(afr, bfr, a2[dt], 0, 0, 0);
                }
            }
        }
        if (n < 66) {
            const int p = 2 * g0 - 1 + n;
            ushort* dst = &T2[n][0];
            if (p >= 0 && p < 1024) {
                float v[16];
#pragma unroll
                for (int dt = 0; dt < 4; ++dt) {
                    float4 cv = *(const float4*)&PL[128 + dt * 16 + quad * 4];
                    v[dt * 4 + 0] = fast_tanh(a2[dt][0] + cv.x);
                    v[dt * 4 + 1] = fast_tanh(a2[dt][1] + cv.y);
                    v[dt * 4 + 2] = fast_tanh(a2[dt][2] + cv.z);
                    v[dt * 4 + 3] = fast_tanh(a2[dt][3] + cv.w);
                }
                float s = 0.f;
#pragma unroll
                for (int i = 0; i < 16; ++i) s += v[i];
                s += __shfl_xor(s, 16, 64);
                s += __shfl_xor(s, 32, 64);
                float mean = s * 0.015625f;
                float qq = 0.f;
#pragma unroll
                for (int i = 0; i < 16; ++i) { float d = v[i] - mean; qq = fmaf(d, d, qq); }
                qq += __shfl_xor(qq, 16, 64);
                qq += __shfl_xor(qq, 32, 64);
                float rstd = rsqrtf(qq * 0.015625f + LN_EPS);
#pragma unroll
                for (int dt = 0; dt < 4; ++dt) {
                    float4 gv = *(const float4*)&PL[192 + dt * 16 + quad * 4];
                    float4 bv = *(const float4*)&PL[256 + dt * 16 + quad * 4];
                    bf16x4 pk;
                    pk[0] = (short)f2bf((v[dt * 4 + 0] - mean) * rstd * gv.x + bv.x);
                    pk[1] = (short)f2bf((v[dt * 4 + 1] - mean) * rstd * gv.y + bv.y);
                    pk[2] = (short)f2bf((v[dt * 4 + 2] - mean) * rstd * gv.z + bv.z);
                    pk[3] = (short)f2bf((v[dt * 4 + 3] - mean) * rstd * gv.w + bv.w);
                    *(bf16x4*)(dst + dt * 16 + quad * 4) = pk;
                }
            } else {
                bf16x4 z; z[0] = 0; z[1] = 0; z[2] = 0; z[3] = 0;
#pragma unroll
                for (int dt = 0; dt < 4; ++dt)
                    *(bf16x4*)(dst + dt * 16 + quad * 4) = z;
            }
        }
    }
    __syncthreads();

    // ================= stage 3: final l = g0 + m3, m3 = wv*16+l15 (wv<2) ===
    if (wv < 2) {
        const int m3 = wv * 16 + l15;
        f32x4 a3[4];
#pragma unroll
        for (int dt = 0; dt < 4; ++dt) a3[dt] = (f32x4)0.f;
        const ushort* Wg3 = Wm23 + 16384;
#pragma unroll
        for (int kk = 0; kk < 4; ++kk) {
            const int row = 2 * m3 + kk;         // <= 65 < 66
#pragma unroll
            for (int k2 = 0; k2 < 2; ++k2) {
                bf16x8 bfr = *(const bf16x8*)&T2[row][k2 * 32 + quad * 8];
                const ushort* wb = Wg3 + ((((kk * 2 + k2) * 4 + quad) * 4) * 16) * 8;
#pragma unroll
                for (int dt = 0; dt < 4; ++dt) {
                    bf16x8 afr = *(const bf16x8*)(wb + ((size_t)(dt * 16 + l15)) * 8);
                    a3[dt] = __builtin_amdgcn_mfma_f32_16x16x32_bf16(afr, bfr, a3[dt], 0, 0, 0);
                }
            }
        }
        const int l = g0 + m3;
        float* ob = out + ((size_t)(b * 512) + l) * 64;
#pragma unroll
        for (int dt = 0; dt < 4; ++dt) {
            float4 cv = *(const float4*)&PL[320 + dt * 16 + quad * 4];
            float4 st = make_float4(fast_tanh(a3[dt][0] + cv.x),
                                    fast_tanh(a3[dt][1] + cv.y),
                                    fast_tanh(a3[dt][2] + cv.z),
                                    fast_tanh(a3[dt][3] + cv.w));
            *(float4*)(ob + dt * 16 + quad * 4) = st;
        }
    }
}

extern "C" void kernel_launch(void* const* d_in, const int* in_sizes, int n_in,
                              void* d_out, int out_size, void* d_ws, size_t ws_size,
                              hipStream_t stream) {
    (void)in_sizes; (void)n_in; (void)out_size; (void)ws_size;
    const float* x   = (const float*)d_in[0];
    const float* w3  = (const float*)d_in[1];
    const float* b3  = (const float*)d_in[2];
    const float* w5  = (const float*)d_in[3];
    const float* b5  = (const float*)d_in[4];
    const float* w7  = (const float*)d_in[5];
    const float* b7  = (const float*)d_in[6];
    const float* w9  = (const float*)d_in[7];
    const float* b9  = (const float*)d_in[8];
    const float* cw1 = (const float*)d_in[9];
    const float* cb1 = (const float*)d_in[10];
    const float* cw2 = (const float*)d_in[11];
    const float* cb2 = (const float*)d_in[12];
    const float* cw3 = (const float*)d_in[13];
    const float* cb3 = (const float*)d_in[14];
    const float* lg1 = (const float*)d_in[15];
    const float* lb1 = (const float*)d_in[16];
    const float* lg2 = (const float*)d_in[17];
    const float* lb2 = (const float*)d_in[18];
    float* out = (float*)d_out;

    // ws layout (bytes) — ~590 KB total, no HBM intermediates:
    char* w = (char*)d_ws;
    ushort* Wm23 = (ushort*)(w + 0);          //  65536 B (2 x 16384 bf16)
    ushort* Wm1  = (ushort*)(w + 65536);      //   4096 B (2048 bf16)
    float*  cbt  = (float*)(w + 69632);       //   1024 B
    float*  W0c  = (float*)(w + 70656);       //   1024 B
    float*  W3c  = (float*)(w + 71680);       //   1024 B
    float*  pe1c = (float*)(w + 72704);       // 524288 B (2048 x 64 fp32)

    prep_kernel<<<128, 256, 0, stream>>>(cw1, cw2, cw3, w3, b3, w5, b5, w7, b7, w9, b9,
                                         Wm23, Wm1, cbt, W0c, W3c);
    pe1_kernel<<<32, 256, 0, stream>>>(cw1, cb1, cbt, pe1c);
    mega_kernel<<<dim3(16, BATCH), 256, 0, stream>>>(
        x, Wm1, Wm23, pe1c, W0c, W3c, lg1, lb1, cb2, lg2, lb2, cb3, out);
}